// Round 3
// baseline (860.170 us; speedup 1.0000x reference)
//
#include <hip/hip_runtime.h>
#include <math.h>

#define N_USERS 100000
#define N_ITEMS 50000
#define N_NODES 150000
#define EMB 64
#define NI 128
#define NUM_EDGES 4000000
#define NPAD 150016            // 586 * 256
#define NB 586                 // buckets of 256 nodes
#define BSTRIDE 8192           // fixed slots per bucket (mean 6827, sigma ~83)
#define NTILES (N_NODES / 16)  // 9375
#define SBLK ((NTILES + 3) / 4) // 2344 blocks x 4 waves
#define EDGE_BLOCKS ((NUM_EDGES + 255) / 256)

typedef __attribute__((ext_vector_type(8))) short bf16x8;
typedef __attribute__((ext_vector_type(4))) float f32x4;

__device__ __forceinline__ unsigned short f2bf(float f) {
    unsigned int u = __float_as_uint(f);
    u += 0x7FFFu + ((u >> 16) & 1u);
    return (unsigned short)(u >> 16);
}
__device__ __forceinline__ float bflo(unsigned int u) { return __uint_as_float(u << 16); }
__device__ __forceinline__ float bfhi(unsigned int u) { return __uint_as_float(u & 0xFFFF0000u); }

// ---- preprocessing: direct-placement CSR build (no sort) ----

__global__ __launch_bounds__(256) void deg_count(const int* __restrict__ h,
                                                 int* __restrict__ deg) {
    int i = blockIdx.x * 256 + threadIdx.x;
    if (i < NUM_EDGES) atomicAdd(&deg[h[i]], 1);
}

// per-bucket exclusive scan -> rmeta (bucket-strided starts), dinv; deg becomes cursor
__global__ __launch_bounds__(256) void node_meta(int* __restrict__ deg,
                                                 int2* __restrict__ rmeta,
                                                 float* __restrict__ dinv) {
    __shared__ int sc[256];
    int b = blockIdx.x, tid = threadIdx.x;
    int node = (b << 8) + tid;
    int c = (node < N_NODES) ? deg[node] : 0;
    sc[tid] = c;
    __syncthreads();
    for (int off = 1; off < 256; off <<= 1) {
        int tv = (tid >= off) ? sc[tid - off] : 0;
        __syncthreads();
        sc[tid] += tv;
        __syncthreads();
    }
    int start = b * BSTRIDE + (sc[tid] - c);
    if (node < N_NODES) {
        rmeta[node] = make_int2(start, c);
        dinv[node] = (c > 0) ? rsqrtf((float)c) : 0.0f;
        deg[node] = start;          // repurpose as placement cursor
    }
}

__global__ __launch_bounds__(256) void place(const int* __restrict__ h,
                                             const int* __restrict__ t,
                                             int* __restrict__ cur,
                                             unsigned int* __restrict__ ebuf) {
    int i = blockIdx.x * 256 + threadIdx.x;
    if (i < NUM_EDGES) {
        int p = atomicAdd(&cur[h[i]], 1);
        ebuf[p] = (unsigned int)t[i];
    }
}

// ---- init: ebf = bf16(concat(user,item)); acc(d_out) = concat fp32 ----

__global__ void init_kernel(const float4* __restrict__ ue4, const float4* __restrict__ ie4,
                            uint2* __restrict__ ebf4, float4* __restrict__ out4) {
    int i = blockIdx.x * blockDim.x + threadIdx.x;
    const int uelems = N_USERS * EMB / 4;
    const int total  = N_NODES * EMB / 4;
    if (i < total) {
        float4 v = (i < uelems) ? ue4[i] : ie4[i - uelems];
        out4[i] = v;
        unsigned int p0 = ((unsigned int)f2bf(v.y) << 16) | f2bf(v.x);
        unsigned int p1 = ((unsigned int)f2bf(v.w) << 16) | f2bf(v.z);
        ebf4[i] = make_uint2(p0, p1);
    }
}

// ---- wconv: W fp32 -> two bf16 global tables (16 KB each, L1/L2-resident) ----
// Wt[intent][dim] (matmul1 B-frags), W2b[dim][intent] (matmul2 B-frags)

__global__ __launch_bounds__(256) void wconv(const float* __restrict__ W,
                                             unsigned short* __restrict__ Wt,
                                             unsigned short* __restrict__ W2b) {
    int i = blockIdx.x * 256 + threadIdx.x;
    if (i < EMB * NI) {
        int d = i >> 7, c = i & 127;
        unsigned short b = f2bf(W[i]);
        W2b[i] = b;                 // [dim][intent]
        Wt[c * EMB + d] = b;        // [intent][dim]
    }
}

// ---- fused SpMM + MFMA intent head (barrier-free) ----
// One 16-row tile per wave. Block = 256 (4 waves). LDS 22528 B -> 7 blocks/CU
// (28 waves = 87.5% ceiling). No __syncthreads anywhere; W frags from global
// bf16 tables (L1-resident).
//
// Phases per wave:
//  1. Gather (both 8-row halves): lane = (qq row 0..7, cc dim-oct 0..7),
//     uint4 loads, 4 edges/row/iter in flight, col+dinv prefetched, results
//     row-scaled -> fw [16][68] f32.
//  2. Matmul1 S = E @ W (A from global ebf, B from global Wt).
//  3. Softmax in-register (shfl 1/2/4/8).
//  4. Matmul2 O = P @ W^T: per 32-intent chunk pack P hi AND lo bf16 -> pw,
//     then MFMA hi + lo (full fp32 precision of P preserved).
//  5. Epilogue: all 64 lanes; nv = fw + O; bf16 out + acc update.
//
// UPool row (per wave) = 1408 floats: fw at [0,1088), pw at [1088,1408).

__global__ __launch_bounds__(256, 7) void spmm_intent(const int2* __restrict__ rmeta,
                                                      const unsigned int* __restrict__ col,
                                                      const float* __restrict__ dinv,
                                                      const unsigned short* __restrict__ ebf,
                                                      unsigned short* __restrict__ ebfout,
                                                      const unsigned short* __restrict__ Wt,
                                                      const unsigned short* __restrict__ W2b,
                                                      float* __restrict__ acc, float scale) {
    __shared__ __align__(16) float UPool[4][1408];   // 22528 B

    int tid = threadIdx.x;
    int wid = tid >> 6, lane = tid & 63;
    int q = lane >> 4, c = lane & 15;        // matmul decomposition
    int qq = lane >> 3, cc = lane & 7;       // gather decomposition
    int tile = blockIdx.x * 4 + wid;
    if (tile >= NTILES) return;
    int rowbase = tile << 4;
    float* fw = &UPool[wid][0];
    unsigned short* pw = (unsigned short*)&UPool[wid][1088];

    // ---- phase 1: gather, two 8-row halves, 4 edges in flight per row ----
#pragma unroll 1
    for (int half = 0; half < 2; ++half) {
        int row = rowbase + half * 8 + qq;
        int2 rm = rmeta[row];
        int s = rm.x, deg = rm.y;
        float dr = dinv[row];
        int dm = deg;
        dm = max(dm, __shfl_xor(dm, 8));
        dm = max(dm, __shfl_xor(dm, 16));
        dm = max(dm, __shfl_xor(dm, 32));
        dm = __builtin_amdgcn_readfirstlane(dm);

        float a0 = 0.f, a1 = 0.f, a2 = 0.f, a3 = 0.f;
        float a4 = 0.f, a5 = 0.f, a6 = 0.f, a7 = 0.f;
        int last = s + ((deg > 0) ? (deg - 1) : 0);
        int ce0 = min((int)col[s], N_NODES - 1);
        int ce1 = min((int)col[min(s + 1, last)], N_NODES - 1);
        int ce2 = min((int)col[min(s + 2, last)], N_NODES - 1);
        int ce3 = min((int)col[min(s + 3, last)], N_NODES - 1);
        float g0 = dinv[ce0], g1 = dinv[ce1], g2 = dinv[ce2], g3 = dinv[ce3];
        const unsigned short* eb = ebf + (cc << 3);
        for (int it = 0; it < dm; it += 4) {
            float gu0 = (it < deg) ? g0 : 0.f;
            float gu1 = (it + 1 < deg) ? g1 : 0.f;
            float gu2 = (it + 2 < deg) ? g2 : 0.f;
            float gu3 = (it + 3 < deg) ? g3 : 0.f;
            uint4 u0 = *(const uint4*)(eb + ((size_t)ce0 << 6));
            uint4 u1 = *(const uint4*)(eb + ((size_t)ce1 << 6));
            uint4 u2 = *(const uint4*)(eb + ((size_t)ce2 << 6));
            uint4 u3 = *(const uint4*)(eb + ((size_t)ce3 << 6));
            int p0 = min(s + it + 4, last), p1 = min(s + it + 5, last);
            int p2 = min(s + it + 6, last), p3 = min(s + it + 7, last);
            ce0 = min((int)col[p0], N_NODES - 1);
            ce1 = min((int)col[p1], N_NODES - 1);
            ce2 = min((int)col[p2], N_NODES - 1);
            ce3 = min((int)col[p3], N_NODES - 1);
            g0 = dinv[ce0]; g1 = dinv[ce1]; g2 = dinv[ce2]; g3 = dinv[ce3];
            a0 = fmaf(gu0, bflo(u0.x), a0); a1 = fmaf(gu0, bfhi(u0.x), a1);
            a2 = fmaf(gu0, bflo(u0.y), a2); a3 = fmaf(gu0, bfhi(u0.y), a3);
            a4 = fmaf(gu0, bflo(u0.z), a4); a5 = fmaf(gu0, bfhi(u0.z), a5);
            a6 = fmaf(gu0, bflo(u0.w), a6); a7 = fmaf(gu0, bfhi(u0.w), a7);
            a0 = fmaf(gu1, bflo(u1.x), a0); a1 = fmaf(gu1, bfhi(u1.x), a1);
            a2 = fmaf(gu1, bflo(u1.y), a2); a3 = fmaf(gu1, bfhi(u1.y), a3);
            a4 = fmaf(gu1, bflo(u1.z), a4); a5 = fmaf(gu1, bfhi(u1.z), a5);
            a6 = fmaf(gu1, bflo(u1.w), a6); a7 = fmaf(gu1, bfhi(u1.w), a7);
            a0 = fmaf(gu2, bflo(u2.x), a0); a1 = fmaf(gu2, bfhi(u2.x), a1);
            a2 = fmaf(gu2, bflo(u2.y), a2); a3 = fmaf(gu2, bfhi(u2.y), a3);
            a4 = fmaf(gu2, bflo(u2.z), a4); a5 = fmaf(gu2, bfhi(u2.z), a5);
            a6 = fmaf(gu2, bflo(u2.w), a6); a7 = fmaf(gu2, bfhi(u2.w), a7);
            a0 = fmaf(gu3, bflo(u3.x), a0); a1 = fmaf(gu3, bfhi(u3.x), a1);
            a2 = fmaf(gu3, bflo(u3.y), a2); a3 = fmaf(gu3, bfhi(u3.y), a3);
            a4 = fmaf(gu3, bflo(u3.z), a4); a5 = fmaf(gu3, bfhi(u3.z), a5);
            a6 = fmaf(gu3, bflo(u3.w), a6); a7 = fmaf(gu3, bfhi(u3.w), a7);
        }
        int fb = (half * 8 + qq) * 68 + (cc << 3);
        fw[fb + 0] = a0 * dr; fw[fb + 1] = a1 * dr;
        fw[fb + 2] = a2 * dr; fw[fb + 3] = a3 * dr;
        fw[fb + 4] = a4 * dr; fw[fb + 5] = a5 * dr;
        fw[fb + 6] = a6 * dr; fw[fb + 7] = a7 * dr;
    }

    // ---- phase 2: matmul1 S = E @ W ----
    const unsigned short* erow = ebf + ((size_t)(rowbase + c) << 6);
    bf16x8 A0 = *(const bf16x8*)(erow + (q << 3));
    bf16x8 A1 = *(const bf16x8*)(erow + 32 + (q << 3));
    f32x4 S[8];
#pragma unroll
    for (int t = 0; t < 8; ++t) {
        bf16x8 B0 = *(const bf16x8*)&Wt[(16 * t + c) * EMB + (q << 3)];
        bf16x8 B1 = *(const bf16x8*)&Wt[(16 * t + c) * EMB + 32 + (q << 3)];
        f32x4 z = {0.f, 0.f, 0.f, 0.f};
        z = __builtin_amdgcn_mfma_f32_16x16x32_bf16(A0, B0, z, 0, 0, 0);
        S[t] = __builtin_amdgcn_mfma_f32_16x16x32_bf16(A1, B1, z, 0, 0, 0);
    }

    // ---- phase 3: softmax over 128 intents, per C-row (row = 4q + r) ----
#pragma unroll
    for (int r = 0; r < 4; ++r) {
        float m = S[0][r];
#pragma unroll
        for (int t = 1; t < 8; ++t) m = fmaxf(m, S[t][r]);
        m = fmaxf(m, __shfl_xor(m, 1)); m = fmaxf(m, __shfl_xor(m, 2));
        m = fmaxf(m, __shfl_xor(m, 4)); m = fmaxf(m, __shfl_xor(m, 8));
        float sum = 0.f;
#pragma unroll
        for (int t = 0; t < 8; ++t) { float ex = __expf(S[t][r] - m); S[t][r] = ex; sum += ex; }
        sum += __shfl_xor(sum, 1); sum += __shfl_xor(sum, 2);
        sum += __shfl_xor(sum, 4); sum += __shfl_xor(sum, 8);
        float inv = 1.0f / sum;
#pragma unroll
        for (int t = 0; t < 8; ++t) S[t][r] *= inv;
    }

    // ---- phase 4: matmul2 O = P @ W^T, hi/lo bf16 split ----
    f32x4 O0 = {0.f, 0.f, 0.f, 0.f}, O1 = O0, O2 = O0, O3 = O0;
#pragma unroll
    for (int s2 = 0; s2 < 4; ++s2) {
        // hi pass: round P to bf16, keep residual in S
#pragma unroll
        for (int h2 = 0; h2 < 2; ++h2) {
            int t = 2 * s2 + h2;
#pragma unroll
            for (int r = 0; r < 4; ++r) {
                float p = S[t][r];
                unsigned short b = f2bf(p);
                pw[(4 * q + r) * 40 + (h2 << 4) + c] = b;
                S[t][r] = p - bflo((unsigned int)b);
            }
        }
        bf16x8 Pf = *(const bf16x8*)&pw[c * 40 + (q << 3)];
        {
            bf16x8 Bf0 = *(const bf16x8*)&W2b[(c) * NI + (s2 << 5) + (q << 3)];
            bf16x8 Bf1 = *(const bf16x8*)&W2b[(16 + c) * NI + (s2 << 5) + (q << 3)];
            O0 = __builtin_amdgcn_mfma_f32_16x16x32_bf16(Pf, Bf0, O0, 0, 0, 0);
            O1 = __builtin_amdgcn_mfma_f32_16x16x32_bf16(Pf, Bf1, O1, 0, 0, 0);
            bf16x8 Bf2 = *(const bf16x8*)&W2b[(32 + c) * NI + (s2 << 5) + (q << 3)];
            bf16x8 Bf3 = *(const bf16x8*)&W2b[(48 + c) * NI + (s2 << 5) + (q << 3)];
            O2 = __builtin_amdgcn_mfma_f32_16x16x32_bf16(Pf, Bf2, O2, 0, 0, 0);
            O3 = __builtin_amdgcn_mfma_f32_16x16x32_bf16(Pf, Bf3, O3, 0, 0, 0);
        }
        // lo pass: residual
#pragma unroll
        for (int h2 = 0; h2 < 2; ++h2) {
            int t = 2 * s2 + h2;
#pragma unroll
            for (int r = 0; r < 4; ++r)
                pw[(4 * q + r) * 40 + (h2 << 4) + c] = f2bf(S[t][r]);
        }
        bf16x8 Pl = *(const bf16x8*)&pw[c * 40 + (q << 3)];
        {
            bf16x8 Bf0 = *(const bf16x8*)&W2b[(c) * NI + (s2 << 5) + (q << 3)];
            bf16x8 Bf1 = *(const bf16x8*)&W2b[(16 + c) * NI + (s2 << 5) + (q << 3)];
            O0 = __builtin_amdgcn_mfma_f32_16x16x32_bf16(Pl, Bf0, O0, 0, 0, 0);
            O1 = __builtin_amdgcn_mfma_f32_16x16x32_bf16(Pl, Bf1, O1, 0, 0, 0);
            bf16x8 Bf2 = *(const bf16x8*)&W2b[(32 + c) * NI + (s2 << 5) + (q << 3)];
            bf16x8 Bf3 = *(const bf16x8*)&W2b[(48 + c) * NI + (s2 << 5) + (q << 3)];
            O2 = __builtin_amdgcn_mfma_f32_16x16x32_bf16(Pl, Bf2, O2, 0, 0, 0);
            O3 = __builtin_amdgcn_mfma_f32_16x16x32_bf16(Pl, Bf3, O3, 0, 0, 0);
        }
    }

    // compiler fence: keep pw (ushort) accesses ordered vs fw (float) aliasing
    asm volatile("" ::: "memory");

    // ---- phase 5: epilogue, all 64 lanes (lane (q,c) owns rows 4q+r) ----
#pragma unroll
    for (int r = 0; r < 4; ++r) {
        int rl = 4 * q + r;
        const float* gr = &fw[rl * 68];
        size_t rbase = ((size_t)(rowbase + rl) << 6);
        float nv0 = gr[c]      + O0[r];
        float nv1 = gr[16 + c] + O1[r];
        float nv2 = gr[32 + c] + O2[r];
        float nv3 = gr[48 + c] + O3[r];
        ebfout[rbase + c]      = f2bf(nv0);
        ebfout[rbase + 16 + c] = f2bf(nv1);
        ebfout[rbase + 32 + c] = f2bf(nv2);
        ebfout[rbase + 48 + c] = f2bf(nv3);
        acc[rbase + c]      = (acc[rbase + c]      + nv0) * scale;
        acc[rbase + 16 + c] = (acc[rbase + 16 + c] + nv1) * scale;
        acc[rbase + 32 + c] = (acc[rbase + 32 + c] + nv2) * scale;
        acc[rbase + 48 + c] = (acc[rbase + 48 + c] + nv3) * scale;
    }
}

// ---- launch ----

extern "C" void kernel_launch(void* const* d_in, const int* in_sizes, int n_in,
                              void* d_out, int out_size, void* d_ws, size_t ws_size,
                              hipStream_t stream) {
    const float* ue = (const float*)d_in[0];
    const float* ie = (const float*)d_in[1];
    const float* W  = (const float*)d_in[2];
    const int*   h  = (const int*)d_in[3];
    const int*   t  = (const int*)d_in[4];
    float* out = (float*)d_out;

    // workspace (4-byte units), ~60 MB total
    int*            deg   = (int*)d_ws;                         // NPAD (later: cursor)
    int2*           rmeta = (int2*)(deg + NPAD);                // NPAD int2
    float*          dinv  = (float*)(rmeta + NPAD);             // NPAD
    unsigned int*   ebuf  = (unsigned int*)(dinv + NPAD);       // NB*BSTRIDE
    unsigned short* Wt    = (unsigned short*)(ebuf + NB * BSTRIDE);  // EMB*NI ushort
    unsigned short* W2b   = Wt + EMB * NI;                           // EMB*NI ushort
    unsigned short* ebfA  = W2b + EMB * NI;                          // NPAD*64 ushort
    unsigned short* ebfB  = ebfA + (size_t)NPAD * EMB;               // NPAD*64 ushort

    hipMemsetAsync(deg, 0, N_NODES * sizeof(int), stream);
    deg_count<<<EDGE_BLOCKS, 256, 0, stream>>>(h, deg);
    node_meta<<<NB, 256, 0, stream>>>(deg, rmeta, dinv);
    place<<<EDGE_BLOCKS, 256, 0, stream>>>(h, t, deg, ebuf);
    init_kernel<<<(N_NODES * EMB / 4 + 255) / 256, 256, 0, stream>>>(
        (const float4*)ue, (const float4*)ie, (uint2*)ebfA, (float4*)out);
    wconv<<<(EMB * NI + 255) / 256, 256, 0, stream>>>(W, Wt, W2b);

    const unsigned int* col = ebuf;
    spmm_intent<<<SBLK, 256, 0, stream>>>(rmeta, col, dinv, ebfA, ebfB, Wt, W2b, out, 1.0f);
    spmm_intent<<<SBLK, 256, 0, stream>>>(rmeta, col, dinv, ebfB, ebfA, Wt, W2b, out, 1.0f / 3.0f);
}

// Round 4
// 485.517 us; speedup vs baseline: 1.7717x; 1.7717x over previous
//
#include <hip/hip_runtime.h>
#include <math.h>

#define N_USERS 100000
#define N_ITEMS 50000
#define N_NODES 150000
#define EMB 64
#define NI 128
#define NUM_EDGES 4000000
#define NPAD 150016            // 586 * 256
#define NB 586                 // buckets of 256 nodes
#define BSTRIDE 8192           // fixed slots per bucket (mean 6827, sigma ~83)
#define ETILE 4096
#define EGRID ((NUM_EDGES + ETILE - 1) / ETILE)   // 977
#define NTILES (N_NODES / 16)  // 9375
#define SBLK ((NTILES + 3) / 4) // 2344 blocks x 4 waves

typedef __attribute__((ext_vector_type(8))) short bf16x8;
typedef __attribute__((ext_vector_type(4))) float f32x4;

__device__ __forceinline__ unsigned short f2bf(float f) {
    unsigned int u = __float_as_uint(f);
    u += 0x7FFFu + ((u >> 16) & 1u);
    return (unsigned short)(u >> 16);
}
__device__ __forceinline__ float bflo(unsigned int u) { return __uint_as_float(u << 16); }
__device__ __forceinline__ float bfhi(unsigned int u) { return __uint_as_float(u & 0xFFFF0000u); }

// ---- bucket scatter: block-aggregated reservations into fixed-stride buckets ----

__global__ __launch_bounds__(256) void bucket_scatter(const int* __restrict__ h,
                                                      const int* __restrict__ t,
                                                      int* __restrict__ gcur,
                                                      unsigned int* __restrict__ ebuf) {
    __shared__ int lc[NB];
    __shared__ int lbase[NB];
    __shared__ int lcur[NB];
    int tid = threadIdx.x;
    for (int i = tid; i < NB; i += 256) lc[i] = 0;
    __syncthreads();
    int base = blockIdx.x * ETILE;
#pragma unroll
    for (int k = 0; k < ETILE / 256; ++k) {
        int idx = base + k * 256 + tid;
        if (idx < NUM_EDGES) atomicAdd(&lc[h[idx] >> 8], 1);
    }
    __syncthreads();
    for (int i = tid; i < NB; i += 256) {
        int c = lc[i];
        lbase[i] = c ? (i * BSTRIDE + atomicAdd(&gcur[i], c)) : 0;
        lcur[i] = 0;
    }
    __syncthreads();
#pragma unroll
    for (int k = 0; k < ETILE / 256; ++k) {
        int idx = base + k * 256 + tid;
        if (idx < NUM_EDGES) {
            int hh = h[idx], tt = t[idx];
            int b = hh >> 8;
            int p = lbase[b] + atomicAdd(&lcur[b], 1);
            int lim = b * BSTRIDE + BSTRIDE - 1;
            p = (p <= lim) ? p : lim;
            ebuf[p] = ((unsigned int)(hh & 255) << 18) | (unsigned int)tt;
        }
    }
}

// ---- per-bucket in-LDS counting sort -> row-sorted col, rmeta=(start,count), dinv ----

__global__ __launch_bounds__(256) void bucket_csr(const int* __restrict__ gcur,
                                                  unsigned int* __restrict__ ebuf,
                                                  int2* __restrict__ rmeta,
                                                  float* __restrict__ dinv) {
    __shared__ unsigned int in_s[BSTRIDE];
    __shared__ unsigned int out_s[BSTRIDE];
    __shared__ int cnt_s[256];
    __shared__ int base_s[256];
    __shared__ int sc[256];
    int b = blockIdx.x, tid = threadIdx.x;
    int s = b * BSTRIDE;
    int n = gcur[b];
    if (n > BSTRIDE) n = BSTRIDE;

    for (int i = tid; i < n; i += 256) in_s[i] = ebuf[s + i];
    cnt_s[tid] = 0;
    __syncthreads();
    for (int i = tid; i < n; i += 256) atomicAdd(&cnt_s[in_s[i] >> 18], 1);
    __syncthreads();

    int c = cnt_s[tid];
    sc[tid] = c;
    __syncthreads();
    for (int off = 1; off < 256; off <<= 1) {
        int tv = (tid >= off) ? sc[tid - off] : 0;
        __syncthreads();
        sc[tid] += tv;
        __syncthreads();
    }
    int excl = sc[tid] - c;
    base_s[tid] = excl;
    int node = (b << 8) + tid;
    rmeta[node] = make_int2(s + excl, c);
    dinv[node] = (c > 0) ? rsqrtf((float)c) : 0.0f;
    cnt_s[tid] = 0;
    __syncthreads();

    for (int i = tid; i < n; i += 256) {
        unsigned int q = in_s[i];
        int hl = (int)(q >> 18);
        int p = base_s[hl] + atomicAdd(&cnt_s[hl], 1);
        out_s[p] = q & 0x3FFFFu;    // pure t index
    }
    __syncthreads();
    for (int i = tid; i < n; i += 256) ebuf[s + i] = out_s[i];
}

// ---- init: ebf = bf16(concat(user,item)); acc(d_out) = concat fp32 ----

__global__ void init_kernel(const float4* __restrict__ ue4, const float4* __restrict__ ie4,
                            uint2* __restrict__ ebf4, float4* __restrict__ out4) {
    int i = blockIdx.x * blockDim.x + threadIdx.x;
    const int uelems = N_USERS * EMB / 4;
    const int total  = N_NODES * EMB / 4;
    if (i < total) {
        float4 v = (i < uelems) ? ue4[i] : ie4[i - uelems];
        out4[i] = v;
        unsigned int p0 = ((unsigned int)f2bf(v.y) << 16) | f2bf(v.x);
        unsigned int p1 = ((unsigned int)f2bf(v.w) << 16) | f2bf(v.z);
        ebf4[i] = make_uint2(p0, p1);
    }
}

// ---- wconv: W fp32 -> two bf16 global tables (16 KB each, L1/L2-resident) ----
// Wt[intent][dim] (matmul1 B-frags), W2b[dim][intent] (matmul2 B-frags)

__global__ __launch_bounds__(256) void wconv(const float* __restrict__ W,
                                             unsigned short* __restrict__ Wt,
                                             unsigned short* __restrict__ W2b) {
    int i = blockIdx.x * 256 + threadIdx.x;
    if (i < EMB * NI) {
        int d = i >> 7, c = i & 127;
        unsigned short b = f2bf(W[i]);
        W2b[i] = b;                 // [dim][intent]
        Wt[c * EMB + d] = b;        // [intent][dim]
    }
}

// ---- fused SpMM + MFMA intent head (barrier-free) ----
// One 16-row tile per wave. Block = 256 (4 waves). LDS 22528 B -> 7 blocks/CU
// (28 waves = 87.5% ceiling). No __syncthreads anywhere; W frags from global
// bf16 tables (L1-resident).

__global__ __launch_bounds__(256, 7) void spmm_intent(const int2* __restrict__ rmeta,
                                                      const unsigned int* __restrict__ col,
                                                      const float* __restrict__ dinv,
                                                      const unsigned short* __restrict__ ebf,
                                                      unsigned short* __restrict__ ebfout,
                                                      const unsigned short* __restrict__ Wt,
                                                      const unsigned short* __restrict__ W2b,
                                                      float* __restrict__ acc, float scale) {
    __shared__ __align__(16) float UPool[4][1408];   // 22528 B

    int tid = threadIdx.x;
    int wid = tid >> 6, lane = tid & 63;
    int q = lane >> 4, c = lane & 15;        // matmul decomposition
    int qq = lane >> 3, cc = lane & 7;       // gather decomposition
    int tile = blockIdx.x * 4 + wid;
    if (tile >= NTILES) return;
    int rowbase = tile << 4;
    float* fw = &UPool[wid][0];
    unsigned short* pw = (unsigned short*)&UPool[wid][1088];

    // ---- phase 1: gather, two 8-row halves, 4 edges in flight per row ----
#pragma unroll 1
    for (int half = 0; half < 2; ++half) {
        int row = rowbase + half * 8 + qq;
        int2 rm = rmeta[row];
        int s = rm.x, deg = rm.y;
        float dr = dinv[row];
        int dm = deg;
        dm = max(dm, __shfl_xor(dm, 8));
        dm = max(dm, __shfl_xor(dm, 16));
        dm = max(dm, __shfl_xor(dm, 32));
        dm = __builtin_amdgcn_readfirstlane(dm);

        float a0 = 0.f, a1 = 0.f, a2 = 0.f, a3 = 0.f;
        float a4 = 0.f, a5 = 0.f, a6 = 0.f, a7 = 0.f;
        int last = s + ((deg > 0) ? (deg - 1) : 0);
        int ce0 = min((int)col[s], N_NODES - 1);
        int ce1 = min((int)col[min(s + 1, last)], N_NODES - 1);
        int ce2 = min((int)col[min(s + 2, last)], N_NODES - 1);
        int ce3 = min((int)col[min(s + 3, last)], N_NODES - 1);
        float g0 = dinv[ce0], g1 = dinv[ce1], g2 = dinv[ce2], g3 = dinv[ce3];
        const unsigned short* eb = ebf + (cc << 3);
        for (int it = 0; it < dm; it += 4) {
            float gu0 = (it < deg) ? g0 : 0.f;
            float gu1 = (it + 1 < deg) ? g1 : 0.f;
            float gu2 = (it + 2 < deg) ? g2 : 0.f;
            float gu3 = (it + 3 < deg) ? g3 : 0.f;
            uint4 u0 = *(const uint4*)(eb + ((size_t)ce0 << 6));
            uint4 u1 = *(const uint4*)(eb + ((size_t)ce1 << 6));
            uint4 u2 = *(const uint4*)(eb + ((size_t)ce2 << 6));
            uint4 u3 = *(const uint4*)(eb + ((size_t)ce3 << 6));
            int p0 = min(s + it + 4, last), p1 = min(s + it + 5, last);
            int p2 = min(s + it + 6, last), p3 = min(s + it + 7, last);
            ce0 = min((int)col[p0], N_NODES - 1);
            ce1 = min((int)col[p1], N_NODES - 1);
            ce2 = min((int)col[p2], N_NODES - 1);
            ce3 = min((int)col[p3], N_NODES - 1);
            g0 = dinv[ce0]; g1 = dinv[ce1]; g2 = dinv[ce2]; g3 = dinv[ce3];
            a0 = fmaf(gu0, bflo(u0.x), a0); a1 = fmaf(gu0, bfhi(u0.x), a1);
            a2 = fmaf(gu0, bflo(u0.y), a2); a3 = fmaf(gu0, bfhi(u0.y), a3);
            a4 = fmaf(gu0, bflo(u0.z), a4); a5 = fmaf(gu0, bfhi(u0.z), a5);
            a6 = fmaf(gu0, bflo(u0.w), a6); a7 = fmaf(gu0, bfhi(u0.w), a7);
            a0 = fmaf(gu1, bflo(u1.x), a0); a1 = fmaf(gu1, bfhi(u1.x), a1);
            a2 = fmaf(gu1, bflo(u1.y), a2); a3 = fmaf(gu1, bfhi(u1.y), a3);
            a4 = fmaf(gu1, bflo(u1.z), a4); a5 = fmaf(gu1, bfhi(u1.z), a5);
            a6 = fmaf(gu1, bflo(u1.w), a6); a7 = fmaf(gu1, bfhi(u1.w), a7);
            a0 = fmaf(gu2, bflo(u2.x), a0); a1 = fmaf(gu2, bfhi(u2.x), a1);
            a2 = fmaf(gu2, bflo(u2.y), a2); a3 = fmaf(gu2, bfhi(u2.y), a3);
            a4 = fmaf(gu2, bflo(u2.z), a4); a5 = fmaf(gu2, bfhi(u2.z), a5);
            a6 = fmaf(gu2, bflo(u2.w), a6); a7 = fmaf(gu2, bfhi(u2.w), a7);
            a0 = fmaf(gu3, bflo(u3.x), a0); a1 = fmaf(gu3, bfhi(u3.x), a1);
            a2 = fmaf(gu3, bflo(u3.y), a2); a3 = fmaf(gu3, bfhi(u3.y), a3);
            a4 = fmaf(gu3, bflo(u3.z), a4); a5 = fmaf(gu3, bfhi(u3.z), a5);
            a6 = fmaf(gu3, bflo(u3.w), a6); a7 = fmaf(gu3, bfhi(u3.w), a7);
        }
        int fb = (half * 8 + qq) * 68 + (cc << 3);
        fw[fb + 0] = a0 * dr; fw[fb + 1] = a1 * dr;
        fw[fb + 2] = a2 * dr; fw[fb + 3] = a3 * dr;
        fw[fb + 4] = a4 * dr; fw[fb + 5] = a5 * dr;
        fw[fb + 6] = a6 * dr; fw[fb + 7] = a7 * dr;
    }

    // ---- phase 2: matmul1 S = E @ W ----
    const unsigned short* erow = ebf + ((size_t)(rowbase + c) << 6);
    bf16x8 A0 = *(const bf16x8*)(erow + (q << 3));
    bf16x8 A1 = *(const bf16x8*)(erow + 32 + (q << 3));
    f32x4 S[8];
#pragma unroll
    for (int t = 0; t < 8; ++t) {
        bf16x8 B0 = *(const bf16x8*)&Wt[(16 * t + c) * EMB + (q << 3)];
        bf16x8 B1 = *(const bf16x8*)&Wt[(16 * t + c) * EMB + 32 + (q << 3)];
        f32x4 z = {0.f, 0.f, 0.f, 0.f};
        z = __builtin_amdgcn_mfma_f32_16x16x32_bf16(A0, B0, z, 0, 0, 0);
        S[t] = __builtin_amdgcn_mfma_f32_16x16x32_bf16(A1, B1, z, 0, 0, 0);
    }

    // ---- phase 3: softmax over 128 intents, per C-row (row = 4q + r) ----
#pragma unroll
    for (int r = 0; r < 4; ++r) {
        float m = S[0][r];
#pragma unroll
        for (int t = 1; t < 8; ++t) m = fmaxf(m, S[t][r]);
        m = fmaxf(m, __shfl_xor(m, 1)); m = fmaxf(m, __shfl_xor(m, 2));
        m = fmaxf(m, __shfl_xor(m, 4)); m = fmaxf(m, __shfl_xor(m, 8));
        float sum = 0.f;
#pragma unroll
        for (int t = 0; t < 8; ++t) { float ex = __expf(S[t][r] - m); S[t][r] = ex; sum += ex; }
        sum += __shfl_xor(sum, 1); sum += __shfl_xor(sum, 2);
        sum += __shfl_xor(sum, 4); sum += __shfl_xor(sum, 8);
        float inv = 1.0f / sum;
#pragma unroll
        for (int t = 0; t < 8; ++t) S[t][r] *= inv;
    }

    // ---- phase 4: matmul2 O = P @ W^T, hi/lo bf16 split ----
    f32x4 O0 = {0.f, 0.f, 0.f, 0.f}, O1 = O0, O2 = O0, O3 = O0;
#pragma unroll
    for (int s2 = 0; s2 < 4; ++s2) {
        // hi pass: round P to bf16, keep residual in S
#pragma unroll
        for (int h2 = 0; h2 < 2; ++h2) {
            int t = 2 * s2 + h2;
#pragma unroll
            for (int r = 0; r < 4; ++r) {
                float p = S[t][r];
                unsigned short b = f2bf(p);
                pw[(4 * q + r) * 40 + (h2 << 4) + c] = b;
                S[t][r] = p - bflo((unsigned int)b);
            }
        }
        bf16x8 Pf = *(const bf16x8*)&pw[c * 40 + (q << 3)];
        {
            bf16x8 Bf0 = *(const bf16x8*)&W2b[(c) * NI + (s2 << 5) + (q << 3)];
            bf16x8 Bf1 = *(const bf16x8*)&W2b[(16 + c) * NI + (s2 << 5) + (q << 3)];
            O0 = __builtin_amdgcn_mfma_f32_16x16x32_bf16(Pf, Bf0, O0, 0, 0, 0);
            O1 = __builtin_amdgcn_mfma_f32_16x16x32_bf16(Pf, Bf1, O1, 0, 0, 0);
            bf16x8 Bf2 = *(const bf16x8*)&W2b[(32 + c) * NI + (s2 << 5) + (q << 3)];
            bf16x8 Bf3 = *(const bf16x8*)&W2b[(48 + c) * NI + (s2 << 5) + (q << 3)];
            O2 = __builtin_amdgcn_mfma_f32_16x16x32_bf16(Pf, Bf2, O2, 0, 0, 0);
            O3 = __builtin_amdgcn_mfma_f32_16x16x32_bf16(Pf, Bf3, O3, 0, 0, 0);
        }
        // lo pass: residual
#pragma unroll
        for (int h2 = 0; h2 < 2; ++h2) {
            int t = 2 * s2 + h2;
#pragma unroll
            for (int r = 0; r < 4; ++r)
                pw[(4 * q + r) * 40 + (h2 << 4) + c] = f2bf(S[t][r]);
        }
        bf16x8 Pl = *(const bf16x8*)&pw[c * 40 + (q << 3)];
        {
            bf16x8 Bf0 = *(const bf16x8*)&W2b[(c) * NI + (s2 << 5) + (q << 3)];
            bf16x8 Bf1 = *(const bf16x8*)&W2b[(16 + c) * NI + (s2 << 5) + (q << 3)];
            O0 = __builtin_amdgcn_mfma_f32_16x16x32_bf16(Pl, Bf0, O0, 0, 0, 0);
            O1 = __builtin_amdgcn_mfma_f32_16x16x32_bf16(Pl, Bf1, O1, 0, 0, 0);
            bf16x8 Bf2 = *(const bf16x8*)&W2b[(32 + c) * NI + (s2 << 5) + (q << 3)];
            bf16x8 Bf3 = *(const bf16x8*)&W2b[(48 + c) * NI + (s2 << 5) + (q << 3)];
            O2 = __builtin_amdgcn_mfma_f32_16x16x32_bf16(Pl, Bf2, O2, 0, 0, 0);
            O3 = __builtin_amdgcn_mfma_f32_16x16x32_bf16(Pl, Bf3, O3, 0, 0, 0);
        }
    }

    // compiler fence: keep pw (ushort) accesses ordered vs fw (float) aliasing
    asm volatile("" ::: "memory");

    // ---- phase 5: epilogue, all 64 lanes (lane (q,c) owns rows 4q+r) ----
#pragma unroll
    for (int r = 0; r < 4; ++r) {
        int rl = 4 * q + r;
        const float* gr = &fw[rl * 68];
        size_t rbase = ((size_t)(rowbase + rl) << 6);
        float nv0 = gr[c]      + O0[r];
        float nv1 = gr[16 + c] + O1[r];
        float nv2 = gr[32 + c] + O2[r];
        float nv3 = gr[48 + c] + O3[r];
        ebfout[rbase + c]      = f2bf(nv0);
        ebfout[rbase + 16 + c] = f2bf(nv1);
        ebfout[rbase + 32 + c] = f2bf(nv2);
        ebfout[rbase + 48 + c] = f2bf(nv3);
        acc[rbase + c]      = (acc[rbase + c]      + nv0) * scale;
        acc[rbase + 16 + c] = (acc[rbase + 16 + c] + nv1) * scale;
        acc[rbase + 32 + c] = (acc[rbase + 32 + c] + nv2) * scale;
        acc[rbase + 48 + c] = (acc[rbase + 48 + c] + nv3) * scale;
    }
}

// ---- launch ----

extern "C" void kernel_launch(void* const* d_in, const int* in_sizes, int n_in,
                              void* d_out, int out_size, void* d_ws, size_t ws_size,
                              hipStream_t stream) {
    const float* ue = (const float*)d_in[0];
    const float* ie = (const float*)d_in[1];
    const float* W  = (const float*)d_in[2];
    const int*   h  = (const int*)d_in[3];
    const int*   t  = (const int*)d_in[4];
    float* out = (float*)d_out;

    // workspace (4-byte units), ~60 MB total
    int*            gcur  = (int*)d_ws;                         // 1024 (NB used)
    int2*           rmeta = (int2*)(gcur + 1024);               // NPAD int2
    float*          dinv  = (float*)(rmeta + NPAD);             // NPAD
    unsigned int*   ebuf  = (unsigned int*)(dinv + NPAD);       // NB*BSTRIDE
    unsigned short* Wt    = (unsigned short*)(ebuf + NB * BSTRIDE);  // EMB*NI ushort
    unsigned short* W2b   = Wt + EMB * NI;                           // EMB*NI ushort
    unsigned short* ebfA  = W2b + EMB * NI;                          // NPAD*64 ushort
    unsigned short* ebfB  = ebfA + (size_t)NPAD * EMB;               // NPAD*64 ushort

    hipMemsetAsync(gcur, 0, NB * sizeof(int), stream);
    bucket_scatter<<<EGRID, 256, 0, stream>>>(h, t, gcur, ebuf);
    bucket_csr<<<NB, 256, 0, stream>>>(gcur, ebuf, rmeta, dinv);
    init_kernel<<<(N_NODES * EMB / 4 + 255) / 256, 256, 0, stream>>>(
        (const float4*)ue, (const float4*)ie, (uint2*)ebfA, (float4*)out);
    wconv<<<(EMB * NI + 255) / 256, 256, 0, stream>>>(W, Wt, W2b);

    const unsigned int* col = ebuf;
    spmm_intent<<<SBLK, 256, 0, stream>>>(rmeta, col, dinv, ebfA, ebfB, Wt, W2b, out, 1.0f);
    spmm_intent<<<SBLK, 256, 0, stream>>>(rmeta, col, dinv, ebfB, ebfA, Wt, W2b, out, 1.0f / 3.0f);
}

// Round 5
// 453.241 us; speedup vs baseline: 1.8978x; 1.0712x over previous
//
#include <hip/hip_runtime.h>
#include <math.h>

#define N_USERS 100000
#define N_ITEMS 50000
#define N_NODES 150000
#define EMB 64
#define NI 128
#define NUM_EDGES 4000000
#define NPAD 150016            // 586 * 256
#define NB 586                 // buckets of 256 nodes
#define BSTRIDE 8192           // fixed slots per bucket (mean 6827, sigma ~83)
#define ETILE 8192
#define EGRID ((NUM_EDGES + ETILE - 1) / ETILE)   // 489
#define NTILES (N_NODES / 16)  // 9375
#define SBLK ((NTILES + 3) / 4) // 2344 blocks x 4 waves

typedef __attribute__((ext_vector_type(8))) short bf16x8;
typedef __attribute__((ext_vector_type(4))) float f32x4;

__device__ __forceinline__ unsigned short f2bf(float f) {
    unsigned int u = __float_as_uint(f);
    u += 0x7FFFu + ((u >> 16) & 1u);
    return (unsigned short)(u >> 16);
}
__device__ __forceinline__ float bflo(unsigned int u) { return __uint_as_float(u << 16); }
__device__ __forceinline__ float bfhi(unsigned int u) { return __uint_as_float(u & 0xFFFF0000u); }
__device__ __forceinline__ int cl_idx(unsigned int v) {
    int x = (int)(v & 0x3FFFFu);
    return (x < N_NODES) ? x : (N_NODES - 1);
}

// ---- bucket scatter: block-aggregated reservations into fixed-stride buckets ----

__global__ __launch_bounds__(512) void bucket_scatter(const int* __restrict__ h,
                                                      const int* __restrict__ t,
                                                      int* __restrict__ gcur,
                                                      unsigned int* __restrict__ ebuf) {
    __shared__ int lc[NB];
    __shared__ int lbase[NB];
    __shared__ int lcur[NB];
    int tid = threadIdx.x;
    for (int i = tid; i < NB; i += 512) lc[i] = 0;
    __syncthreads();
    int base = blockIdx.x * ETILE;
#pragma unroll
    for (int k = 0; k < ETILE / 512; ++k) {
        int idx = base + k * 512 + tid;
        if (idx < NUM_EDGES) atomicAdd(&lc[h[idx] >> 8], 1);
    }
    __syncthreads();
    for (int i = tid; i < NB; i += 512) {
        int c = lc[i];
        lbase[i] = c ? (i * BSTRIDE + atomicAdd(&gcur[i], c)) : 0;
        lcur[i] = 0;
    }
    __syncthreads();
#pragma unroll
    for (int k = 0; k < ETILE / 512; ++k) {
        int idx = base + k * 512 + tid;
        if (idx < NUM_EDGES) {
            int hh = h[idx], tt = t[idx];
            int b = hh >> 8;
            int p = lbase[b] + atomicAdd(&lcur[b], 1);
            int lim = b * BSTRIDE + BSTRIDE - 1;
            p = (p <= lim) ? p : lim;
            ebuf[p] = ((unsigned int)(hh & 255) << 18) | (unsigned int)tt;
        }
    }
}

// ---- per-bucket in-LDS counting sort (single-staged, 512 thr) ----
// LDS 35 KB -> 4 blocks/CU; final placement written straight to global (L2).

__global__ __launch_bounds__(512) void bucket_csr(const int* __restrict__ gcur,
                                                  unsigned int* __restrict__ ebuf,
                                                  int2* __restrict__ rmeta,
                                                  float* __restrict__ dinv) {
    __shared__ unsigned int in_s[BSTRIDE];   // 32 KB
    __shared__ int cnt_s[256];
    __shared__ int base_s[256];
    __shared__ int sc[256];
    int b = blockIdx.x, tid = threadIdx.x;
    int s = b * BSTRIDE;
    int n = gcur[b];
    if (n > BSTRIDE) n = BSTRIDE;

    for (int i = tid; i < n; i += 512) in_s[i] = ebuf[s + i];
    if (tid < 256) cnt_s[tid] = 0;
    __syncthreads();
    for (int i = tid; i < n; i += 512) atomicAdd(&cnt_s[in_s[i] >> 18], 1);
    __syncthreads();

    int c = 0;
    if (tid < 256) { c = cnt_s[tid]; sc[tid] = c; }
    __syncthreads();
    for (int off = 1; off < 256; off <<= 1) {
        int tv = 0;
        if (tid < 256 && tid >= off) tv = sc[tid - off];
        __syncthreads();
        if (tid < 256 && tid >= off) sc[tid] += tv;
        __syncthreads();
    }
    if (tid < 256) {
        int excl = sc[tid] - c;
        base_s[tid] = excl;
        int node = (b << 8) + tid;
        rmeta[node] = make_int2(s + excl, c);
        dinv[node] = (c > 0) ? rsqrtf((float)c) : 0.0f;
        cnt_s[tid] = 0;
    }
    __syncthreads();

    for (int i = tid; i < n; i += 512) {
        unsigned int qv = in_s[i];
        int hl = (int)(qv >> 18);
        int p = base_s[hl] + atomicAdd(&cnt_s[hl], 1);
        ebuf[s + p] = qv & 0x3FFFFu;    // pure t index, sorted position (via L2)
    }
}

// ---- init: ebf = bf16(concat(user,item)); acc(d_out) = concat fp32 ----

__global__ void init_kernel(const float4* __restrict__ ue4, const float4* __restrict__ ie4,
                            uint2* __restrict__ ebf4, float4* __restrict__ out4) {
    int i = blockIdx.x * blockDim.x + threadIdx.x;
    const int uelems = N_USERS * EMB / 4;
    const int total  = N_NODES * EMB / 4;
    if (i < total) {
        float4 v = (i < uelems) ? ue4[i] : ie4[i - uelems];
        out4[i] = v;
        unsigned int p0 = ((unsigned int)f2bf(v.y) << 16) | f2bf(v.x);
        unsigned int p1 = ((unsigned int)f2bf(v.w) << 16) | f2bf(v.z);
        ebf4[i] = make_uint2(p0, p1);
    }
}

// ---- wconv: W fp32 -> two bf16 global tables (16 KB each, L1/L2-resident) ----

__global__ __launch_bounds__(256) void wconv(const float* __restrict__ W,
                                             unsigned short* __restrict__ Wt,
                                             unsigned short* __restrict__ W2b) {
    int i = blockIdx.x * 256 + threadIdx.x;
    if (i < EMB * NI) {
        int d = i >> 7, c = i & 127;
        unsigned short b = f2bf(W[i]);
        W2b[i] = b;                 // [dim][intent]
        Wt[c * EMB + d] = b;        // [intent][dim]
    }
}

// ---- fused SpMM + MFMA intent head (barrier-free) ----
// One 16-row tile per wave. Block = 256 (4 waves). LDS 22528 B.
// __launch_bounds__(256,6): VGPR cap 85 for the 2-deep gather pipeline.
//
// Gather: lane = (qq row 0..7, cc dim-oct 0..7); software-pipelined 2 deep:
//   col kept 2 groups ahead, dinv+uint4 issued 1 group ahead, FMA consumes
//   the previous group's loads -> no load consumed in its issue iteration.
// Epilogue: O folded into fw (LDS), then lanes re-mapped to (row, 16-float
//   segment) for uint4/float4 fully-coalesced global writes.

__global__ __launch_bounds__(256, 6) void spmm_intent(const int2* __restrict__ rmeta,
                                                      const unsigned int* __restrict__ col,
                                                      const float* __restrict__ dinv,
                                                      const unsigned short* __restrict__ ebf,
                                                      unsigned short* __restrict__ ebfout,
                                                      const unsigned short* __restrict__ Wt,
                                                      const unsigned short* __restrict__ W2b,
                                                      float* __restrict__ acc, float scale) {
    __shared__ __align__(16) float UPool[4][1408];   // 22528 B

    int tid = threadIdx.x;
    int wid = tid >> 6, lane = tid & 63;
    int q = lane >> 4, c = lane & 15;        // matmul decomposition
    int qq = lane >> 3, cc = lane & 7;       // gather decomposition
    int tile = blockIdx.x * 4 + wid;
    if (tile >= NTILES) return;
    int rowbase = tile << 4;
    float* fw = &UPool[wid][0];
    unsigned short* pw = (unsigned short*)&UPool[wid][1088];

    // ---- phase 1: gather, two 8-row halves, 2-deep pipelined, 4 edges/group ----
#pragma unroll 1
    for (int half = 0; half < 2; ++half) {
        int row = rowbase + half * 8 + qq;
        int2 rm = rmeta[row];
        int s = rm.x, deg = rm.y;
        float dr = dinv[row];
        int dm = deg;
        dm = max(dm, __shfl_xor(dm, 8));
        dm = max(dm, __shfl_xor(dm, 16));
        dm = max(dm, __shfl_xor(dm, 32));
        dm = __builtin_amdgcn_readfirstlane(dm);

        float a0 = 0.f, a1 = 0.f, a2 = 0.f, a3 = 0.f;
        float a4 = 0.f, a5 = 0.f, a6 = 0.f, a7 = 0.f;
        int last = s + ((deg > 0) ? (deg - 1) : 0);
        const unsigned short* eb = ebf + (cc << 3);

        // prologue: group0 fully loaded; group1 col values staged
        int ce0 = cl_idx(col[s]);
        int ce1 = cl_idx(col[min(s + 1, last)]);
        int ce2 = cl_idx(col[min(s + 2, last)]);
        int ce3 = cl_idx(col[min(s + 3, last)]);
        float g0 = dinv[ce0], g1 = dinv[ce1], g2 = dinv[ce2], g3 = dinv[ce3];
        uint4 u0 = *(const uint4*)(eb + ((size_t)ce0 << 6));
        uint4 u1 = *(const uint4*)(eb + ((size_t)ce1 << 6));
        uint4 u2 = *(const uint4*)(eb + ((size_t)ce2 << 6));
        uint4 u3 = *(const uint4*)(eb + ((size_t)ce3 << 6));
        int nc0 = cl_idx(col[min(s + 4, last)]);
        int nc1 = cl_idx(col[min(s + 5, last)]);
        int nc2 = cl_idx(col[min(s + 6, last)]);
        int nc3 = cl_idx(col[min(s + 7, last)]);

        for (int it = 0; it < dm; it += 4) {
            // issue col for group it+8 (consumed in 2 iterations)
            int f0 = cl_idx(col[min(s + it + 8, last)]);
            int f1 = cl_idx(col[min(s + it + 9, last)]);
            int f2 = cl_idx(col[min(s + it + 10, last)]);
            int f3 = cl_idx(col[min(s + it + 11, last)]);
            // issue dinv + embedding loads for group it+4 (consumed next iter)
            float h0 = dinv[nc0], h1 = dinv[nc1], h2 = dinv[nc2], h3 = dinv[nc3];
            uint4 v0 = *(const uint4*)(eb + ((size_t)nc0 << 6));
            uint4 v1 = *(const uint4*)(eb + ((size_t)nc1 << 6));
            uint4 v2 = *(const uint4*)(eb + ((size_t)nc2 << 6));
            uint4 v3 = *(const uint4*)(eb + ((size_t)nc3 << 6));
            // consume group it (loaded last iteration)
            float gu0 = (it     < deg) ? g0 : 0.f;
            float gu1 = (it + 1 < deg) ? g1 : 0.f;
            float gu2 = (it + 2 < deg) ? g2 : 0.f;
            float gu3 = (it + 3 < deg) ? g3 : 0.f;
            a0 = fmaf(gu0, bflo(u0.x), a0); a1 = fmaf(gu0, bfhi(u0.x), a1);
            a2 = fmaf(gu0, bflo(u0.y), a2); a3 = fmaf(gu0, bfhi(u0.y), a3);
            a4 = fmaf(gu0, bflo(u0.z), a4); a5 = fmaf(gu0, bfhi(u0.z), a5);
            a6 = fmaf(gu0, bflo(u0.w), a6); a7 = fmaf(gu0, bfhi(u0.w), a7);
            a0 = fmaf(gu1, bflo(u1.x), a0); a1 = fmaf(gu1, bfhi(u1.x), a1);
            a2 = fmaf(gu1, bflo(u1.y), a2); a3 = fmaf(gu1, bfhi(u1.y), a3);
            a4 = fmaf(gu1, bflo(u1.z), a4); a5 = fmaf(gu1, bfhi(u1.z), a5);
            a6 = fmaf(gu1, bflo(u1.w), a6); a7 = fmaf(gu1, bfhi(u1.w), a7);
            a0 = fmaf(gu2, bflo(u2.x), a0); a1 = fmaf(gu2, bfhi(u2.x), a1);
            a2 = fmaf(gu2, bflo(u2.y), a2); a3 = fmaf(gu2, bfhi(u2.y), a3);
            a4 = fmaf(gu2, bflo(u2.z), a4); a5 = fmaf(gu2, bfhi(u2.z), a5);
            a6 = fmaf(gu2, bflo(u2.w), a6); a7 = fmaf(gu2, bfhi(u2.w), a7);
            a0 = fmaf(gu3, bflo(u3.x), a0); a1 = fmaf(gu3, bfhi(u3.x), a1);
            a2 = fmaf(gu3, bflo(u3.y), a2); a3 = fmaf(gu3, bfhi(u3.y), a3);
            a4 = fmaf(gu3, bflo(u3.z), a4); a5 = fmaf(gu3, bfhi(u3.z), a5);
            a6 = fmaf(gu3, bflo(u3.w), a6); a7 = fmaf(gu3, bfhi(u3.w), a7);
            // rotate pipeline
            u0 = v0; u1 = v1; u2 = v2; u3 = v3;
            g0 = h0; g1 = h1; g2 = h2; g3 = h3;
            nc0 = f0; nc1 = f1; nc2 = f2; nc3 = f3;
        }
        int fb = (half * 8 + qq) * 68 + (cc << 3);
        fw[fb + 0] = a0 * dr; fw[fb + 1] = a1 * dr;
        fw[fb + 2] = a2 * dr; fw[fb + 3] = a3 * dr;
        fw[fb + 4] = a4 * dr; fw[fb + 5] = a5 * dr;
        fw[fb + 6] = a6 * dr; fw[fb + 7] = a7 * dr;
    }

    // ---- phase 2: matmul1 S = E @ W ----
    const unsigned short* erow = ebf + ((size_t)(rowbase + c) << 6);
    bf16x8 A0 = *(const bf16x8*)(erow + (q << 3));
    bf16x8 A1 = *(const bf16x8*)(erow + 32 + (q << 3));
    f32x4 S[8];
#pragma unroll
    for (int t = 0; t < 8; ++t) {
        bf16x8 B0 = *(const bf16x8*)&Wt[(16 * t + c) * EMB + (q << 3)];
        bf16x8 B1 = *(const bf16x8*)&Wt[(16 * t + c) * EMB + 32 + (q << 3)];
        f32x4 z = {0.f, 0.f, 0.f, 0.f};
        z = __builtin_amdgcn_mfma_f32_16x16x32_bf16(A0, B0, z, 0, 0, 0);
        S[t] = __builtin_amdgcn_mfma_f32_16x16x32_bf16(A1, B1, z, 0, 0, 0);
    }

    // ---- phase 3: softmax over 128 intents, per C-row (row = 4q + r) ----
#pragma unroll
    for (int r = 0; r < 4; ++r) {
        float m = S[0][r];
#pragma unroll
        for (int t = 1; t < 8; ++t) m = fmaxf(m, S[t][r]);
        m = fmaxf(m, __shfl_xor(m, 1)); m = fmaxf(m, __shfl_xor(m, 2));
        m = fmaxf(m, __shfl_xor(m, 4)); m = fmaxf(m, __shfl_xor(m, 8));
        float sum = 0.f;
#pragma unroll
        for (int t = 0; t < 8; ++t) { float ex = __expf(S[t][r] - m); S[t][r] = ex; sum += ex; }
        sum += __shfl_xor(sum, 1); sum += __shfl_xor(sum, 2);
        sum += __shfl_xor(sum, 4); sum += __shfl_xor(sum, 8);
        float inv = 1.0f / sum;
#pragma unroll
        for (int t = 0; t < 8; ++t) S[t][r] *= inv;
    }

    // ---- phase 4: matmul2 O = P @ W^T, hi/lo bf16 split ----
    f32x4 O0 = {0.f, 0.f, 0.f, 0.f}, O1 = O0, O2 = O0, O3 = O0;
#pragma unroll
    for (int s2 = 0; s2 < 4; ++s2) {
        // hi pass: round P to bf16, keep residual in S
#pragma unroll
        for (int h2 = 0; h2 < 2; ++h2) {
            int t = 2 * s2 + h2;
#pragma unroll
            for (int r = 0; r < 4; ++r) {
                float p = S[t][r];
                unsigned short b = f2bf(p);
                pw[(4 * q + r) * 40 + (h2 << 4) + c] = b;
                S[t][r] = p - bflo((unsigned int)b);
            }
        }
        bf16x8 Pf = *(const bf16x8*)&pw[c * 40 + (q << 3)];
        {
            bf16x8 Bf0 = *(const bf16x8*)&W2b[(c) * NI + (s2 << 5) + (q << 3)];
            bf16x8 Bf1 = *(const bf16x8*)&W2b[(16 + c) * NI + (s2 << 5) + (q << 3)];
            O0 = __builtin_amdgcn_mfma_f32_16x16x32_bf16(Pf, Bf0, O0, 0, 0, 0);
            O1 = __builtin_amdgcn_mfma_f32_16x16x32_bf16(Pf, Bf1, O1, 0, 0, 0);
            bf16x8 Bf2 = *(const bf16x8*)&W2b[(32 + c) * NI + (s2 << 5) + (q << 3)];
            bf16x8 Bf3 = *(const bf16x8*)&W2b[(48 + c) * NI + (s2 << 5) + (q << 3)];
            O2 = __builtin_amdgcn_mfma_f32_16x16x32_bf16(Pf, Bf2, O2, 0, 0, 0);
            O3 = __builtin_amdgcn_mfma_f32_16x16x32_bf16(Pf, Bf3, O3, 0, 0, 0);
        }
        // lo pass: residual
#pragma unroll
        for (int h2 = 0; h2 < 2; ++h2) {
            int t = 2 * s2 + h2;
#pragma unroll
            for (int r = 0; r < 4; ++r)
                pw[(4 * q + r) * 40 + (h2 << 4) + c] = f2bf(S[t][r]);
        }
        bf16x8 Pl = *(const bf16x8*)&pw[c * 40 + (q << 3)];
        {
            bf16x8 Bf0 = *(const bf16x8*)&W2b[(c) * NI + (s2 << 5) + (q << 3)];
            bf16x8 Bf1 = *(const bf16x8*)&W2b[(16 + c) * NI + (s2 << 5) + (q << 3)];
            O0 = __builtin_amdgcn_mfma_f32_16x16x32_bf16(Pl, Bf0, O0, 0, 0, 0);
            O1 = __builtin_amdgcn_mfma_f32_16x16x32_bf16(Pl, Bf1, O1, 0, 0, 0);
            bf16x8 Bf2 = *(const bf16x8*)&W2b[(32 + c) * NI + (s2 << 5) + (q << 3)];
            bf16x8 Bf3 = *(const bf16x8*)&W2b[(48 + c) * NI + (s2 << 5) + (q << 3)];
            O2 = __builtin_amdgcn_mfma_f32_16x16x32_bf16(Pl, Bf2, O2, 0, 0, 0);
            O3 = __builtin_amdgcn_mfma_f32_16x16x32_bf16(Pl, Bf3, O3, 0, 0, 0);
        }
    }

    // compiler fence: keep pw (ushort) accesses ordered vs fw (float) accesses
    asm volatile("" ::: "memory");

    // ---- phase 5a: fold O into fw (nv = gnn + O), wave-local ----
#pragma unroll
    for (int r = 0; r < 4; ++r) {
        int rl = 4 * q + r;
        float* gr = &fw[rl * 68];
        gr[c]      += O0[r];
        gr[16 + c] += O1[r];
        gr[32 + c] += O2[r];
        gr[48 + c] += O3[r];
    }

    // ---- phase 5b: coalesced write-out; lane = (row j, 16-float segment sg) ----
    {
        int j = lane >> 2, sg = lane & 3;
        const float* gr = &fw[j * 68 + (sg << 4)];
        float4 x0 = *(const float4*)&gr[0];
        float4 x1 = *(const float4*)&gr[4];
        float4 x2 = *(const float4*)&gr[8];
        float4 x3 = *(const float4*)&gr[12];
        size_t base = ((size_t)(rowbase + j) << 6) + (sg << 4);   // element index
        uint4 w0, w1;
        w0.x = (unsigned int)f2bf(x0.x) | ((unsigned int)f2bf(x0.y) << 16);
        w0.y = (unsigned int)f2bf(x0.z) | ((unsigned int)f2bf(x0.w) << 16);
        w0.z = (unsigned int)f2bf(x1.x) | ((unsigned int)f2bf(x1.y) << 16);
        w0.w = (unsigned int)f2bf(x1.z) | ((unsigned int)f2bf(x1.w) << 16);
        w1.x = (unsigned int)f2bf(x2.x) | ((unsigned int)f2bf(x2.y) << 16);
        w1.y = (unsigned int)f2bf(x2.z) | ((unsigned int)f2bf(x2.w) << 16);
        w1.z = (unsigned int)f2bf(x3.x) | ((unsigned int)f2bf(x3.y) << 16);
        w1.w = (unsigned int)f2bf(x3.z) | ((unsigned int)f2bf(x3.w) << 16);
        *(uint4*)(ebfout + base) = w0;
        *(uint4*)(ebfout + base + 8) = w1;
        float4* ap = (float4*)(acc + base);
        float4 b0 = ap[0], b1 = ap[1], b2 = ap[2], b3 = ap[3];
        b0.x = (b0.x + x0.x) * scale; b0.y = (b0.y + x0.y) * scale;
        b0.z = (b0.z + x0.z) * scale; b0.w = (b0.w + x0.w) * scale;
        b1.x = (b1.x + x1.x) * scale; b1.y = (b1.y + x1.y) * scale;
        b1.z = (b1.z + x1.z) * scale; b1.w = (b1.w + x1.w) * scale;
        b2.x = (b2.x + x2.x) * scale; b2.y = (b2.y + x2.y) * scale;
        b2.z = (b2.z + x2.z) * scale; b2.w = (b2.w + x2.w) * scale;
        b3.x = (b3.x + x3.x) * scale; b3.y = (b3.y + x3.y) * scale;
        b3.z = (b3.z + x3.z) * scale; b3.w = (b3.w + x3.w) * scale;
        ap[0] = b0; ap[1] = b1; ap[2] = b2; ap[3] = b3;
    }
}

// ---- launch ----

extern "C" void kernel_launch(void* const* d_in, const int* in_sizes, int n_in,
                              void* d_out, int out_size, void* d_ws, size_t ws_size,
                              hipStream_t stream) {
    const float* ue = (const float*)d_in[0];
    const float* ie = (const float*)d_in[1];
    const float* W  = (const float*)d_in[2];
    const int*   h  = (const int*)d_in[3];
    const int*   t  = (const int*)d_in[4];
    float* out = (float*)d_out;

    // workspace (4-byte units), ~60 MB total
    int*            gcur  = (int*)d_ws;                         // 1024 (NB used)
    int2*           rmeta = (int2*)(gcur + 1024);               // NPAD int2
    float*          dinv  = (float*)(rmeta + NPAD);             // NPAD
    unsigned int*   ebuf  = (unsigned int*)(dinv + NPAD);       // NB*BSTRIDE
    unsigned short* Wt    = (unsigned short*)(ebuf + NB * BSTRIDE);  // EMB*NI ushort
    unsigned short* W2b   = Wt + EMB * NI;                           // EMB*NI ushort
    unsigned short* ebfA  = W2b + EMB * NI;                          // NPAD*64 ushort
    unsigned short* ebfB  = ebfA + (size_t)NPAD * EMB;               // NPAD*64 ushort

    hipMemsetAsync(gcur, 0, NB * sizeof(int), stream);
    bucket_scatter<<<EGRID, 512, 0, stream>>>(h, t, gcur, ebuf);
    bucket_csr<<<NB, 512, 0, stream>>>(gcur, ebuf, rmeta, dinv);
    init_kernel<<<(N_NODES * EMB / 4 + 255) / 256, 256, 0, stream>>>(
        (const float4*)ue, (const float4*)ie, (uint2*)ebfA, (float4*)out);
    wconv<<<(EMB * NI + 255) / 256, 256, 0, stream>>>(W, Wt, W2b);

    const unsigned int* col = ebuf;
    spmm_intent<<<SBLK, 256, 0, stream>>>(rmeta, col, dinv, ebfA, ebfB, Wt, W2b, out, 1.0f);
    spmm_intent<<<SBLK, 256, 0, stream>>>(rmeta, col, dinv, ebfB, ebfA, Wt, W2b, out, 1.0f / 3.0f);
}